// Round 1
// baseline (2406.000 us; speedup 1.0000x reference)
//
#include <hip/hip_runtime.h>
#include <math.h>

#define DIM   128
#define NV    (DIM*DIM*DIM)          // 2097152 per volume; 4 volumes total
#define SM    1e-6f
#define NITER 40
#define INV27 (1.0f/27.0f)

// meta (float) layout in ws:
//  [0..79]   sums[iter*2 + g]  (g=0: pred group, g=1: target group)
//  [96..101] acc[b*3 + {inter, sum_p, sum_t}], b in {0,1}
//  [104]     flag (pred max > 1)
//  [256...]  bufA (4*NV), then bufB (4*NV)
#define ACC_OFF  96
#define FLAG_OFF 104
#define BUF_OFF  256

__global__ __launch_bounds__(256)
void k_init_meta(float* meta) { meta[threadIdx.x] = 0.0f; }

__global__ __launch_bounds__(256)
void k_flag(const float* __restrict__ pred, float* __restrict__ meta, int n) {
    int stride = gridDim.x * blockDim.x;
    bool hit = false;
    for (int i = blockIdx.x * blockDim.x + threadIdx.x; i < n; i += stride)
        hit |= (pred[i] > 1.0f);
    if (hit) meta[FLAG_OFF] = 1.0f;   // same-value racing stores: benign
}

__global__ __launch_bounds__(256)
void k_prep(const float* __restrict__ pred, const float* __restrict__ tgt,
            const float* __restrict__ meta, float* __restrict__ bufA, int n) {
    const bool useSig = (meta[FLAG_OFF] != 0.0f);
    int stride = gridDim.x * blockDim.x;
    for (int i = blockIdx.x * blockDim.x + threadIdx.x; i < n; i += stride) {
        float p = pred[i];
        if (useSig) p = 1.0f / (1.0f + expf(-p));
        bufA[i] = fminf(fmaxf(p, 0.0f), 1.0f);
        float t = tgt[i];
        bufA[2 * NV + i] = fminf(fmaxf(t, 0.0f), 1.0f);
    }
}

// Fused skeletonize step: new = clip_done( skel * (1 - clip(avg3(clip(avg3(skel)-sm))) + sm) )
// Block: 16x16 threads = 16x16 columns (12x12 interior outputs), z-chunk of 32 (+4 halo planes).
__global__ __launch_bounds__(256)
void k_step(const float* __restrict__ src, float* __restrict__ dst,
            float* __restrict__ sums, int iter) {
    __shared__ float sIn[16][16];
    __shared__ float sRs[16][16];
    __shared__ float sEr[16][16];
    __shared__ float sRs2[16][16];
    __shared__ float sRed[256];
    __shared__ float sDone;

    const int x = threadIdx.x, y = threadIdx.y;
    const int tid = y * 16 + x;
    const int t   = blockIdx.x;
    const int txt = t % 11;
    const int tyt = (t / 11) % 11;
    const int tzc = t / 121;           // 0..3
    const int vol = blockIdx.y;        // 0,1 = pred b0,b1 ; 2,3 = tgt b0,b1
    const int g   = vol >> 1;

    if (tid == 0) {
        float df = 0.0f;
        for (int j = 0; j < iter; ++j)
            if (sums[j * 2 + g] < SM) df = 1.0f;
        sDone = df;
    }
    __syncthreads();
    const float done = sDone;

    const int gx = txt * 12 - 2 + x;
    const int gy = tyt * 12 - 2 + y;
    const bool colIn  = (gx >= 0) && (gx < DIM) && (gy >= 0) && (gy < DIM);
    const bool midCol = (x >= 1) && (x <= 14) && (y >= 1) && (y <= 14);
    const bool outCol = (x >= 2) && (x <= 13) && (y >= 2) && (y <= 13) &&
                        (gx < DIM) && (gy < DIM);
    const int z0 = tzc * 32;

    const float* sp = src + (size_t)vol * NV;
    float*       dp = dst + (size_t)vol * NV;

    float s2d_m1 = 0.f, s2d_m2 = 0.f;
    float e2d_m1 = 0.f, e2d_m2 = 0.f;
    float v_m1 = 0.f, v_m2 = 0.f;
    float localSum = 0.f;

    for (int zg = z0 - 2; zg <= z0 + 33; ++zg) {
        // --- load plane zg ---
        float v = 0.0f;
        if (colIn && zg >= 0 && zg < DIM)
            v = sp[((size_t)zg * DIM + gy) * DIM + gx];
        sIn[y][x] = v;
        __syncthreads();                                   // B1
        // --- x row-sum of input ---
        float rs = 0.0f;
        if (x >= 1 && x <= 14)
            rs = sIn[y][x - 1] + sIn[y][x] + sIn[y][x + 1];
        sRs[y][x] = rs;
        __syncthreads();                                   // B2
        // --- 2D 3x3 sum; rolling z -> eroded plane (zg-1) ---
        float s2d = 0.0f;
        if (midCol)
            s2d = sRs[y - 1][x] + sRs[y][x] + sRs[y + 1][x];
        const int ze = zg - 1;
        float er = 0.0f;
        if (colIn && midCol && ze >= 0 && ze < DIM) {
            float e = (s2d_m2 + s2d_m1 + s2d) * INV27 - SM;
            er = fminf(fmaxf(e, 0.0f), 1.0f);
        }
        s2d_m2 = s2d_m1; s2d_m1 = s2d;
        sEr[y][x] = er;
        __syncthreads();                                   // B3
        // --- x row-sum of eroded ---
        float rs2 = 0.0f;
        if (x >= 2 && x <= 13)
            rs2 = sEr[y][x - 1] + sEr[y][x] + sEr[y][x + 1];
        sRs2[y][x] = rs2;
        __syncthreads();                                   // B4
        // --- 2D sum of eroded; rolling z -> opened plane (zg-2); emit ---
        float e2d = 0.0f;
        if (x >= 2 && x <= 13 && y >= 2 && y <= 13)
            e2d = sRs2[y - 1][x] + sRs2[y][x] + sRs2[y + 1][x];
        const int zo = zg - 2;
        if (zo >= z0 && outCol) {
            float op = fminf(fmaxf((e2d_m2 + e2d_m1 + e2d) * INV27, 0.0f), 1.0f);
            float nv = v_m2 * (1.0f - op + SM);
            nv = (done != 0.0f) ? v_m2 : nv;
            dp[((size_t)zo * DIM + gy) * DIM + gx] = nv;
            localSum += nv;
        }
        e2d_m2 = e2d_m1; e2d_m1 = e2d;
        v_m2 = v_m1;     v_m1 = v;
    }

    // block-reduce localSum -> sums[iter*2+g]
    __syncthreads();
    sRed[tid] = localSum;
    __syncthreads();
    for (int s = 128; s > 0; s >>= 1) {
        if (tid < s) sRed[tid] += sRed[tid + s];
        __syncthreads();
    }
    if (tid == 0) atomicAdd(&sums[iter * 2 + g], sRed[0]);
}

__global__ __launch_bounds__(256)
void k_dice(const float* __restrict__ buf, float* __restrict__ acc) {
    __shared__ float sA[256], sB[256], sC[256];
    const int b = blockIdx.y;
    const float* p = buf + (size_t)b * NV;
    const float* t = buf + (size_t)(2 + b) * NV;
    float si = 0.f, spv = 0.f, stv = 0.f;
    int stride = gridDim.x * blockDim.x;
    for (int i = blockIdx.x * blockDim.x + threadIdx.x; i < NV; i += stride) {
        float pv = p[i], tv = t[i];
        si += pv * tv; spv += pv; stv += tv;
    }
    const int tid = threadIdx.x;
    sA[tid] = si; sB[tid] = spv; sC[tid] = stv;
    __syncthreads();
    for (int s = 128; s > 0; s >>= 1) {
        if (tid < s) { sA[tid] += sA[tid + s]; sB[tid] += sB[tid + s]; sC[tid] += sC[tid + s]; }
        __syncthreads();
    }
    if (tid == 0) {
        atomicAdd(&acc[b * 3 + 0], sA[0]);
        atomicAdd(&acc[b * 3 + 1], sB[0]);
        atomicAdd(&acc[b * 3 + 2], sC[0]);
    }
}

__global__ void k_fin(const float* __restrict__ acc, float* __restrict__ out) {
    float loss = 0.0f;
    for (int b = 0; b < 2; ++b) {
        float inter = acc[b * 3 + 0], spv = acc[b * 3 + 1], stv = acc[b * 3 + 2];
        float dice = (2.0f * inter + SM) / (spv + stv + SM);
        loss += 1.0f - dice;
    }
    out[0] = 0.5f * loss;
}

extern "C" void kernel_launch(void* const* d_in, const int* in_sizes, int n_in,
                              void* d_out, int out_size, void* d_ws, size_t ws_size,
                              hipStream_t stream) {
    (void)in_sizes; (void)n_in; (void)out_size; (void)ws_size;
    const float* pred = (const float*)d_in[0];
    const float* tgt  = (const float*)d_in[1];
    float* out  = (float*)d_out;
    float* meta = (float*)d_ws;
    float* bufA = meta + BUF_OFF;
    float* bufB = bufA + (size_t)4 * NV;

    k_init_meta<<<dim3(1), dim3(256), 0, stream>>>(meta);
    k_flag<<<dim3(1024), dim3(256), 0, stream>>>(pred, meta, 2 * NV);
    k_prep<<<dim3(2048), dim3(256), 0, stream>>>(pred, tgt, meta, bufA, 2 * NV);

    dim3 sgrid(11 * 11 * 4, 4);
    dim3 sblock(16, 16);
    for (int it = 0; it < NITER; ++it) {
        const float* s = (it & 1) ? bufB : bufA;
        float*       d = (it & 1) ? bufA : bufB;
        k_step<<<sgrid, sblock, 0, stream>>>(s, d, meta, it);
    }

    k_dice<<<dim3(512, 2), dim3(256), 0, stream>>>(bufA, meta + ACC_OFF);
    k_fin<<<dim3(1), dim3(1), 0, stream>>>(meta + ACC_OFF, out);
}

// Round 2
// 1257.532 us; speedup vs baseline: 1.9133x; 1.9133x over previous
//
#include <hip/hip_runtime.h>
#include <math.h>

#define DIM   128
#define NV    (DIM*DIM*DIM)          // 2097152 per volume; 4 volumes total
#define SM    1e-6f
#define NITER 40
#define INV27 (1.0f/27.0f)
#define ACC_OFF  96
#define FLAG_OFF 104
#define BUF_OFF  256
#define YT 20                        // thread rows (16 interior + 2 halo each side)
#define ZC 16                        // z outputs per block

__device__ __forceinline__ float c01(float v){ return fminf(fmaxf(v, 0.f), 1.f); }

__global__ __launch_bounds__(256)
void k_init_meta(float* meta) { meta[threadIdx.x] = 0.0f; }

__global__ __launch_bounds__(256)
void k_flag(const float4* __restrict__ pred, float* __restrict__ meta, int n4) {
    int stride = gridDim.x * blockDim.x;
    bool hit = false;
    for (int i = blockIdx.x * blockDim.x + threadIdx.x; i < n4; i += stride) {
        float4 p = pred[i];
        hit |= (p.x > 1.f) | (p.y > 1.f) | (p.z > 1.f) | (p.w > 1.f);
    }
    if (hit) meta[FLAG_OFF] = 1.0f;   // same-value racing stores: benign
}

__global__ __launch_bounds__(256)
void k_prep(const float4* __restrict__ pred, const float4* __restrict__ tgt,
            const float* __restrict__ meta, float4* __restrict__ outP,
            float4* __restrict__ outT, int n4) {
    const bool sg = (meta[FLAG_OFF] != 0.0f);
    int stride = gridDim.x * blockDim.x;
    for (int i = blockIdx.x * blockDim.x + threadIdx.x; i < n4; i += stride) {
        float4 p = pred[i];
        if (sg) {
            p.x = 1.f / (1.f + __expf(-p.x));
            p.y = 1.f / (1.f + __expf(-p.y));
            p.z = 1.f / (1.f + __expf(-p.z));
            p.w = 1.f / (1.f + __expf(-p.w));
        }
        p.x = c01(p.x); p.y = c01(p.y); p.z = c01(p.z); p.w = c01(p.w);
        outP[i] = p;
        float4 t = tgt[i];
        t.x = c01(t.x); t.y = c01(t.y); t.z = c01(t.z); t.w = c01(t.w);
        outT[i] = t;
    }
}

// Fused skeletonize step, 1 barrier per plane.
// Block: 16x20 threads; each thread owns 8 contiguous x (full 128-row per 16 threads).
// Pipeline at loop index Z: load v(Z) -> rs(Z)[shuffles] -> store rs(Z),rs2(Z-2)
// -> barrier -> s2d(Z) -> er(Z-1) -> rs2(Z-1)[shuffles] -> e2d(Z-2) -> emit(Z-3).
__global__ __launch_bounds__(320)
void k_step(const float* __restrict__ src, float* __restrict__ dst,
            float* __restrict__ sums, int iter) {
    __shared__ float4 sA4[2][YT][33];   // input row-sums  (halves at [x], [16+x]; 33 pads rows)
    __shared__ float4 sB4[2][YT][33];   // eroded row-sums
    __shared__ float  sRed[5];
    __shared__ float  sDone;

    const int x    = threadIdx.x;          // 0..15
    const int y    = threadIdx.y;          // 0..19
    const int tid  = y * 16 + x;
    const int lane = tid & 63;
    const int ytile = blockIdx.x & 7;
    const int zch   = blockIdx.x >> 3;
    const int vol   = blockIdx.y;          // 0,1 pred; 2,3 target
    const int g     = vol >> 1;
    const int z0    = zch * ZC;
    const int gy    = ytile * 16 - 2 + y;
    const bool rowIn = (gy >= 0) && (gy < DIM);
    const bool midY  = (y >= 1) && (y <= 18);
    const bool outY  = (y >= 2) && (y <= 17);

    // early-stop flag: done = OR_{j<iter} sums[j] < SM (parallel over wave 0)
    if (tid < 64) {
        bool hit = (tid < iter) && (sums[tid * 2 + g] < SM);
        unsigned long long m = __ballot(hit);
        if (lane == 0) sDone = (m != 0ull) ? 1.0f : 0.0f;
    }
    __syncthreads();
    const bool done = (sDone != 0.0f);

    const float* sp = src + (size_t)vol * NV;
    float*       dp = dst + (size_t)vol * NV;

    const float4 z4 = make_float4(0.f, 0.f, 0.f, 0.f);
    float4 vm1A = z4, vm1B = z4, vm2A = z4, vm2B = z4, vm3A = z4, vm3B = z4;
    float4 s1A = z4, s1B = z4, s2A = z4, s2B = z4;   // s2d history (m1, m2)
    float4 r2A = z4, r2B = z4;                       // rs2(Z-2), stored this iter
    float4 g1A = z4, g1B = z4, g2A = z4, g2B = z4;   // e2d history (m1, m2)
    float  localSum = 0.f;

    for (int Z = z0 - 2; Z <= z0 + ZC + 2; ++Z) {
        const int p = Z & 1;
        // ---- load plane Z (skip final pipeline-drain iter) ----
        float4 vA = z4, vB = z4;
        if (rowIn && Z >= 0 && Z < DIM && Z <= z0 + ZC + 1) {
            const float4* q = (const float4*)(sp + ((size_t)Z * DIM + gy) * DIM + x * 8);
            vA = q[0]; vB = q[1];
        }
        // ---- x row-sum of v via shuffles ----
        float lft = __shfl(vB.w, lane - 1); if (x == 0)  lft = 0.f;
        float rgt = __shfl(vA.x, lane + 1); if (x == 15) rgt = 0.f;
        float4 rsA, rsB;
        rsA.x = lft  + vA.x + vA.y;  rsA.y = vA.x + vA.y + vA.z;
        rsA.z = vA.y + vA.z + vA.w;  rsA.w = vA.z + vA.w + vB.x;
        rsB.x = vA.w + vB.x + vB.y;  rsB.y = vB.x + vB.y + vB.z;
        rsB.z = vB.y + vB.z + vB.w;  rsB.w = vB.z + vB.w + rgt;

        sA4[p][y][x] = rsA;  sA4[p][y][16 + x] = rsB;
        sB4[p][y][x] = r2A;  sB4[p][y][16 + x] = r2B;
        __syncthreads();

        const int ym = (y > 0) ? y - 1 : 0;
        const int yp = (y < YT - 1) ? y + 1 : YT - 1;
        // ---- 2D sum of input, rolling z -> eroded plane Z-1 ----
        float4 uA = sA4[p][ym][x], uB = sA4[p][ym][16 + x];
        float4 dA = sA4[p][yp][x], dB = sA4[p][yp][16 + x];
        float4 sdA, sdB;
        sdA.x = uA.x + rsA.x + dA.x;  sdA.y = uA.y + rsA.y + dA.y;
        sdA.z = uA.z + rsA.z + dA.z;  sdA.w = uA.w + rsA.w + dA.w;
        sdB.x = uB.x + rsB.x + dB.x;  sdB.y = uB.y + rsB.y + dB.y;
        sdB.z = uB.z + rsB.z + dB.z;  sdB.w = uB.w + rsB.w + dB.w;

        const bool erOk = midY && rowIn && (Z - 1 >= 0) && (Z - 1 < DIM);
        float4 erA = z4, erB = z4;
        if (erOk) {
            erA.x = c01((s2A.x + s1A.x + sdA.x) * INV27 - SM);
            erA.y = c01((s2A.y + s1A.y + sdA.y) * INV27 - SM);
            erA.z = c01((s2A.z + s1A.z + sdA.z) * INV27 - SM);
            erA.w = c01((s2A.w + s1A.w + sdA.w) * INV27 - SM);
            erB.x = c01((s2B.x + s1B.x + sdB.x) * INV27 - SM);
            erB.y = c01((s2B.y + s1B.y + sdB.y) * INV27 - SM);
            erB.z = c01((s2B.z + s1B.z + sdB.z) * INV27 - SM);
            erB.w = c01((s2B.w + s1B.w + sdB.w) * INV27 - SM);
        }
        s2A = s1A; s1A = sdA;  s2B = s1B; s1B = sdB;

        // ---- x row-sum of eroded via shuffles -> rs2(Z-1), stored next iter ----
        float lft2 = __shfl(erB.w, lane - 1); if (x == 0)  lft2 = 0.f;
        float rgt2 = __shfl(erA.x, lane + 1); if (x == 15) rgt2 = 0.f;
        float4 r2nA, r2nB;
        r2nA.x = lft2  + erA.x + erA.y;  r2nA.y = erA.x + erA.y + erA.z;
        r2nA.z = erA.y + erA.z + erA.w;  r2nA.w = erA.z + erA.w + erB.x;
        r2nB.x = erA.w + erB.x + erB.y;  r2nB.y = erB.x + erB.y + erB.z;
        r2nB.z = erB.y + erB.z + erB.w;  r2nB.w = erB.z + erB.w + rgt2;

        // ---- 2D sum of eroded, plane Z-2 ----
        float4 euA = sB4[p][ym][x], euB = sB4[p][ym][16 + x];
        float4 edA = sB4[p][yp][x], edB = sB4[p][yp][16 + x];
        float4 e2A, e2B;
        e2A.x = euA.x + r2A.x + edA.x;  e2A.y = euA.y + r2A.y + edA.y;
        e2A.z = euA.z + r2A.z + edA.z;  e2A.w = euA.w + r2A.w + edA.w;
        e2B.x = euB.x + r2B.x + edB.x;  e2B.y = euB.y + r2B.y + edB.y;
        e2B.z = euB.z + r2B.z + edB.z;  e2B.w = euB.w + r2B.w + edB.w;

        // ---- opened plane Z-3, emit ----
        const int zo = Z - 3;
        if (zo >= z0 && outY) {
            float4 opA, opB, nvA, nvB;
            opA.x = c01((g2A.x + g1A.x + e2A.x) * INV27);
            opA.y = c01((g2A.y + g1A.y + e2A.y) * INV27);
            opA.z = c01((g2A.z + g1A.z + e2A.z) * INV27);
            opA.w = c01((g2A.w + g1A.w + e2A.w) * INV27);
            opB.x = c01((g2B.x + g1B.x + e2B.x) * INV27);
            opB.y = c01((g2B.y + g1B.y + e2B.y) * INV27);
            opB.z = c01((g2B.z + g1B.z + e2B.z) * INV27);
            opB.w = c01((g2B.w + g1B.w + e2B.w) * INV27);
            nvA.x = vm3A.x * (1.f - opA.x + SM);  nvA.y = vm3A.y * (1.f - opA.y + SM);
            nvA.z = vm3A.z * (1.f - opA.z + SM);  nvA.w = vm3A.w * (1.f - opA.w + SM);
            nvB.x = vm3B.x * (1.f - opB.x + SM);  nvB.y = vm3B.y * (1.f - opB.y + SM);
            nvB.z = vm3B.z * (1.f - opB.z + SM);  nvB.w = vm3B.w * (1.f - opB.w + SM);
            if (done) { nvA = vm3A; nvB = vm3B; }
            float4* o = (float4*)(dp + ((size_t)zo * DIM + gy) * DIM + x * 8);
            o[0] = nvA; o[1] = nvB;
            localSum += nvA.x + nvA.y + nvA.z + nvA.w + nvB.x + nvB.y + nvB.z + nvB.w;
        }
        g2A = g1A; g1A = e2A;  g2B = g1B; g1B = e2B;
        vm3A = vm2A; vm2A = vm1A; vm1A = vA;
        vm3B = vm2B; vm2B = vm1B; vm1B = vB;
        r2A = r2nA;  r2B = r2nB;
    }

    // ---- block reduce localSum -> sums[iter*2+g] ----
    float s = localSum;
    for (int off = 32; off > 0; off >>= 1) s += __shfl_down(s, off);
    if (lane == 0) sRed[tid >> 6] = s;
    __syncthreads();
    if (tid == 0) {
        atomicAdd(&sums[iter * 2 + g], sRed[0] + sRed[1] + sRed[2] + sRed[3] + sRed[4]);
    }
}

__global__ __launch_bounds__(256)
void k_dice(const float* __restrict__ buf, float* __restrict__ acc) {
    __shared__ float sA[256], sB[256], sC[256];
    const int b = blockIdx.y;
    const float4* p = (const float4*)(buf + (size_t)b * NV);
    const float4* t = (const float4*)(buf + (size_t)(2 + b) * NV);
    float si = 0.f, spv = 0.f, stv = 0.f;
    int stride = gridDim.x * blockDim.x;
    for (int i = blockIdx.x * blockDim.x + threadIdx.x; i < NV / 4; i += stride) {
        float4 pv = p[i], tv = t[i];
        si  += pv.x * tv.x + pv.y * tv.y + pv.z * tv.z + pv.w * tv.w;
        spv += pv.x + pv.y + pv.z + pv.w;
        stv += tv.x + tv.y + tv.z + tv.w;
    }
    const int tid = threadIdx.x;
    sA[tid] = si; sB[tid] = spv; sC[tid] = stv;
    __syncthreads();
    for (int s = 128; s > 0; s >>= 1) {
        if (tid < s) { sA[tid] += sA[tid + s]; sB[tid] += sB[tid + s]; sC[tid] += sC[tid + s]; }
        __syncthreads();
    }
    if (tid == 0) {
        atomicAdd(&acc[b * 3 + 0], sA[0]);
        atomicAdd(&acc[b * 3 + 1], sB[0]);
        atomicAdd(&acc[b * 3 + 2], sC[0]);
    }
}

__global__ void k_fin(const float* __restrict__ acc, float* __restrict__ out) {
    float loss = 0.0f;
    for (int b = 0; b < 2; ++b) {
        float inter = acc[b * 3 + 0], spv = acc[b * 3 + 1], stv = acc[b * 3 + 2];
        float dice = (2.0f * inter + SM) / (spv + stv + SM);
        loss += 1.0f - dice;
    }
    out[0] = 0.5f * loss;
}

extern "C" void kernel_launch(void* const* d_in, const int* in_sizes, int n_in,
                              void* d_out, int out_size, void* d_ws, size_t ws_size,
                              hipStream_t stream) {
    (void)in_sizes; (void)n_in; (void)out_size; (void)ws_size;
    const float* pred = (const float*)d_in[0];
    const float* tgt  = (const float*)d_in[1];
    float* out  = (float*)d_out;
    float* meta = (float*)d_ws;
    float* bufA = meta + BUF_OFF;
    float* bufB = bufA + (size_t)4 * NV;

    k_init_meta<<<dim3(1), dim3(256), 0, stream>>>(meta);
    k_flag<<<dim3(1024), dim3(256), 0, stream>>>((const float4*)pred, meta, 2 * NV / 4);
    k_prep<<<dim3(1024), dim3(256), 0, stream>>>((const float4*)pred, (const float4*)tgt,
                                                 meta, (float4*)bufA,
                                                 (float4*)(bufA + (size_t)2 * NV), 2 * NV / 4);

    dim3 sgrid(8 * (DIM / ZC), 4);   // ytiles * zchunks, volumes
    dim3 sblock(16, YT);
    for (int it = 0; it < NITER; ++it) {
        const float* s = (it & 1) ? bufB : bufA;
        float*       d = (it & 1) ? bufA : bufB;
        k_step<<<sgrid, sblock, 0, stream>>>(s, d, meta, it);
    }

    k_dice<<<dim3(512, 2), dim3(256), 0, stream>>>(bufA, meta + ACC_OFF);
    k_fin<<<dim3(1), dim3(1), 0, stream>>>(meta + ACC_OFF, out);
}

// Round 3
// 1247.514 us; speedup vs baseline: 1.9286x; 1.0080x over previous
//
#include <hip/hip_runtime.h>
#include <math.h>

#define DIM   128
#define NV    (DIM*DIM*DIM)          // 2097152 per volume; 4 volumes total
#define SM    1e-6f
#define NITER 40
#define INV27 (1.0f/27.0f)
#define ACC_OFF  96
#define FLAG_OFF 104
#define BUF_OFF  256
#define YT 20                        // thread rows (16 interior + 2 halo each side)
#define ZC 16                        // z outputs per block

__device__ __forceinline__ float c01(float v){ return fminf(fmaxf(v, 0.f), 1.f); }

__global__ __launch_bounds__(256)
void k_init_meta(float* meta) { meta[threadIdx.x] = 0.0f; }

__global__ __launch_bounds__(256)
void k_flag(const float4* __restrict__ pred, float* __restrict__ meta, int n4) {
    int stride = gridDim.x * blockDim.x;
    bool hit = false;
    for (int i = blockIdx.x * blockDim.x + threadIdx.x; i < n4; i += stride) {
        float4 p = pred[i];
        hit |= (p.x > 1.f) | (p.y > 1.f) | (p.z > 1.f) | (p.w > 1.f);
    }
    if (hit) meta[FLAG_OFF] = 1.0f;   // same-value racing stores: benign
}

__global__ __launch_bounds__(256)
void k_prep(const float4* __restrict__ pred, const float4* __restrict__ tgt,
            const float* __restrict__ meta, float4* __restrict__ outP,
            float4* __restrict__ outT, int n4) {
    const bool sg = (meta[FLAG_OFF] != 0.0f);
    int stride = gridDim.x * blockDim.x;
    for (int i = blockIdx.x * blockDim.x + threadIdx.x; i < n4; i += stride) {
        float4 p = pred[i];
        if (sg) {
            p.x = 1.f / (1.f + __expf(-p.x));
            p.y = 1.f / (1.f + __expf(-p.y));
            p.z = 1.f / (1.f + __expf(-p.z));
            p.w = 1.f / (1.f + __expf(-p.w));
        }
        p.x = c01(p.x); p.y = c01(p.y); p.z = c01(p.z); p.w = c01(p.w);
        outP[i] = p;
        float4 t = tgt[i];
        t.x = c01(t.x); t.y = c01(t.y); t.z = c01(t.z); t.w = c01(t.w);
        outT[i] = t;
    }
}

// Fused skeletonize step, 1 barrier per plane, next-plane register prefetch.
__global__ __launch_bounds__(320)
void k_step(const float* __restrict__ src, float* __restrict__ dst,
            float* __restrict__ sums, int iter) {
    __shared__ float4 sA4[2][YT][33];   // input row-sums  (halves at [x], [16+x])
    __shared__ float4 sB4[2][YT][33];   // eroded row-sums
    __shared__ float  sRed[5];
    __shared__ float  sDone;

    const int x    = threadIdx.x;          // 0..15
    const int y    = threadIdx.y;          // 0..19
    const int tid  = y * 16 + x;
    const int lane = tid & 63;
    const int ytile = blockIdx.x & 7;
    const int zch   = blockIdx.x >> 3;
    const int vol   = blockIdx.y;          // 0,1 pred; 2,3 target
    const int g     = vol >> 1;
    const int z0    = zch * ZC;
    const int gy    = ytile * 16 - 2 + y;
    const bool rowIn = (gy >= 0) && (gy < DIM);
    const bool midY  = (y >= 1) && (y <= 18);
    const bool outY  = (y >= 2) && (y <= 17);

    if (tid < 64) {
        bool hit = (tid < iter) && (sums[tid * 2 + g] < SM);
        unsigned long long m = __ballot(hit);
        if (lane == 0) sDone = (m != 0ull) ? 1.0f : 0.0f;
    }
    __syncthreads();
    const bool done = (sDone != 0.0f);

    const float* sp = src + (size_t)vol * NV + (size_t)gy * DIM + x * 8;
    float*       dp = dst + (size_t)vol * NV + (size_t)gy * DIM + x * 8;

    const float4 z4 = make_float4(0.f, 0.f, 0.f, 0.f);
    float4 vm1A = z4, vm1B = z4, vm2A = z4, vm2B = z4, vm3A = z4, vm3B = z4;
    float4 s1A = z4, s1B = z4, s2A = z4, s2B = z4;
    float4 r2A = z4, r2B = z4;
    float4 g1A = z4, g1B = z4, g2A = z4, g2B = z4;
    float  localSum = 0.f;

    // prefetch first plane
    float4 nA = z4, nB = z4;
    {
        const int Zf = z0 - 2;
        if (rowIn && Zf >= 0) {
            const float4* q = (const float4*)(sp + (size_t)Zf * (DIM * DIM));
            nA = q[0]; nB = q[1];
        }
    }

    for (int Z = z0 - 2; Z <= z0 + ZC + 2; ++Z) {
        const int p = Z & 1;
        const float4 vA = nA, vB = nB;
        // ---- issue prefetch of plane Z+1 (consumed after next barrier) ----
        nA = z4; nB = z4;
        const int Zn = Z + 1;
        if (rowIn && Zn >= 0 && Zn < DIM && Zn <= z0 + ZC + 1) {
            const float4* q = (const float4*)(sp + (size_t)Zn * (DIM * DIM));
            nA = q[0]; nB = q[1];
        }
        // ---- x row-sum of v via shuffles ----
        float lft = __shfl(vB.w, lane - 1); if (x == 0)  lft = 0.f;
        float rgt = __shfl(vA.x, lane + 1); if (x == 15) rgt = 0.f;
        float4 rsA, rsB;
        rsA.x = lft  + vA.x + vA.y;  rsA.y = vA.x + vA.y + vA.z;
        rsA.z = vA.y + vA.z + vA.w;  rsA.w = vA.z + vA.w + vB.x;
        rsB.x = vA.w + vB.x + vB.y;  rsB.y = vB.x + vB.y + vB.z;
        rsB.z = vB.y + vB.z + vB.w;  rsB.w = vB.z + vB.w + rgt;

        sA4[p][y][x] = rsA;  sA4[p][y][16 + x] = rsB;
        sB4[p][y][x] = r2A;  sB4[p][y][16 + x] = r2B;
        __syncthreads();

        const int ym = (y > 0) ? y - 1 : 0;
        const int yp = (y < YT - 1) ? y + 1 : YT - 1;
        // ---- 2D sum of input, rolling z -> eroded plane Z-1 ----
        float4 uA = sA4[p][ym][x], uB = sA4[p][ym][16 + x];
        float4 dA = sA4[p][yp][x], dB = sA4[p][yp][16 + x];
        float4 sdA, sdB;
        sdA.x = uA.x + rsA.x + dA.x;  sdA.y = uA.y + rsA.y + dA.y;
        sdA.z = uA.z + rsA.z + dA.z;  sdA.w = uA.w + rsA.w + dA.w;
        sdB.x = uB.x + rsB.x + dB.x;  sdB.y = uB.y + rsB.y + dB.y;
        sdB.z = uB.z + rsB.z + dB.z;  sdB.w = uB.w + rsB.w + dB.w;

        const bool erOk = midY && rowIn && (Z - 1 >= 0) && (Z - 1 < DIM);
        float4 erA = z4, erB = z4;
        if (erOk) {
            erA.x = c01((s2A.x + s1A.x + sdA.x) * INV27 - SM);
            erA.y = c01((s2A.y + s1A.y + sdA.y) * INV27 - SM);
            erA.z = c01((s2A.z + s1A.z + sdA.z) * INV27 - SM);
            erA.w = c01((s2A.w + s1A.w + sdA.w) * INV27 - SM);
            erB.x = c01((s2B.x + s1B.x + sdB.x) * INV27 - SM);
            erB.y = c01((s2B.y + s1B.y + sdB.y) * INV27 - SM);
            erB.z = c01((s2B.z + s1B.z + sdB.z) * INV27 - SM);
            erB.w = c01((s2B.w + s1B.w + sdB.w) * INV27 - SM);
        }
        s2A = s1A; s1A = sdA;  s2B = s1B; s1B = sdB;

        // ---- x row-sum of eroded -> rs2(Z-1), stored next iter ----
        float lft2 = __shfl(erB.w, lane - 1); if (x == 0)  lft2 = 0.f;
        float rgt2 = __shfl(erA.x, lane + 1); if (x == 15) rgt2 = 0.f;
        float4 r2nA, r2nB;
        r2nA.x = lft2  + erA.x + erA.y;  r2nA.y = erA.x + erA.y + erA.z;
        r2nA.z = erA.y + erA.z + erA.w;  r2nA.w = erA.z + erA.w + erB.x;
        r2nB.x = erA.w + erB.x + erB.y;  r2nB.y = erB.x + erB.y + erB.z;
        r2nB.z = erB.y + erB.z + erB.w;  r2nB.w = erB.z + erB.w + rgt2;

        // ---- 2D sum of eroded, plane Z-2 ----
        float4 euA = sB4[p][ym][x], euB = sB4[p][ym][16 + x];
        float4 edA = sB4[p][yp][x], edB = sB4[p][yp][16 + x];
        float4 e2A, e2B;
        e2A.x = euA.x + r2A.x + edA.x;  e2A.y = euA.y + r2A.y + edA.y;
        e2A.z = euA.z + r2A.z + edA.z;  e2A.w = euA.w + r2A.w + edA.w;
        e2B.x = euB.x + r2B.x + edB.x;  e2B.y = euB.y + r2B.y + edB.y;
        e2B.z = euB.z + r2B.z + edB.z;  e2B.w = euB.w + r2B.w + edB.w;

        // ---- opened plane Z-3, emit ----
        const int zo = Z - 3;
        if (zo >= z0 && outY) {
            float4 opA, opB, nvA, nvB;
            opA.x = c01((g2A.x + g1A.x + e2A.x) * INV27);
            opA.y = c01((g2A.y + g1A.y + e2A.y) * INV27);
            opA.z = c01((g2A.z + g1A.z + e2A.z) * INV27);
            opA.w = c01((g2A.w + g1A.w + e2A.w) * INV27);
            opB.x = c01((g2B.x + g1B.x + e2B.x) * INV27);
            opB.y = c01((g2B.y + g1B.y + e2B.y) * INV27);
            opB.z = c01((g2B.z + g1B.z + e2B.z) * INV27);
            opB.w = c01((g2B.w + g1B.w + e2B.w) * INV27);
            nvA.x = vm3A.x * (1.f - opA.x + SM);  nvA.y = vm3A.y * (1.f - opA.y + SM);
            nvA.z = vm3A.z * (1.f - opA.z + SM);  nvA.w = vm3A.w * (1.f - opA.w + SM);
            nvB.x = vm3B.x * (1.f - opB.x + SM);  nvB.y = vm3B.y * (1.f - opB.y + SM);
            nvB.z = vm3B.z * (1.f - opB.z + SM);  nvB.w = vm3B.w * (1.f - opB.w + SM);
            if (done) { nvA = vm3A; nvB = vm3B; }
            float4* o = (float4*)(dp + (size_t)zo * (DIM * DIM));
            o[0] = nvA; o[1] = nvB;
            localSum += nvA.x + nvA.y + nvA.z + nvA.w + nvB.x + nvB.y + nvB.z + nvB.w;
        }
        g2A = g1A; g1A = e2A;  g2B = g1B; g1B = e2B;
        vm3A = vm2A; vm2A = vm1A; vm1A = vA;
        vm3B = vm2B; vm2B = vm1B; vm1B = vB;
        r2A = r2nA;  r2B = r2nB;
    }

    // ---- block reduce localSum -> sums[iter*2+g] ----
    float s = localSum;
    for (int off = 32; off > 0; off >>= 1) s += __shfl_down(s, off);
    if (lane == 0) sRed[tid >> 6] = s;
    __syncthreads();
    if (tid == 0) {
        atomicAdd(&sums[iter * 2 + g], sRed[0] + sRed[1] + sRed[2] + sRed[3] + sRed[4]);
    }
}

// One pass, 8 independent float4 loads per thread. grid = (512, 2)
__global__ __launch_bounds__(256)
void k_dice(const float* __restrict__ buf, float* __restrict__ acc) {
    __shared__ float sA[4], sB[4], sC[4];
    const int b = blockIdx.y;
    const float4* p = (const float4*)(buf + (size_t)b * NV);
    const float4* t = (const float4*)(buf + (size_t)(2 + b) * NV);
    const int tid  = threadIdx.x;
    const int lane = tid & 63;
    const int base = blockIdx.x * 1024 + tid;

    float4 pv0 = p[base], pv1 = p[base + 256], pv2 = p[base + 512], pv3 = p[base + 768];
    float4 tv0 = t[base], tv1 = t[base + 256], tv2 = t[base + 512], tv3 = t[base + 768];

    float si  = pv0.x*tv0.x + pv0.y*tv0.y + pv0.z*tv0.z + pv0.w*tv0.w
              + pv1.x*tv1.x + pv1.y*tv1.y + pv1.z*tv1.z + pv1.w*tv1.w
              + pv2.x*tv2.x + pv2.y*tv2.y + pv2.z*tv2.z + pv2.w*tv2.w
              + pv3.x*tv3.x + pv3.y*tv3.y + pv3.z*tv3.z + pv3.w*tv3.w;
    float spv = pv0.x+pv0.y+pv0.z+pv0.w + pv1.x+pv1.y+pv1.z+pv1.w
              + pv2.x+pv2.y+pv2.z+pv2.w + pv3.x+pv3.y+pv3.z+pv3.w;
    float stv = tv0.x+tv0.y+tv0.z+tv0.w + tv1.x+tv1.y+tv1.z+tv1.w
              + tv2.x+tv2.y+tv2.z+tv2.w + tv3.x+tv3.y+tv3.z+tv3.w;

    for (int off = 32; off > 0; off >>= 1) {
        si  += __shfl_down(si, off);
        spv += __shfl_down(spv, off);
        stv += __shfl_down(stv, off);
    }
    if (lane == 0) { sA[tid >> 6] = si; sB[tid >> 6] = spv; sC[tid >> 6] = stv; }
    __syncthreads();
    if (tid == 0) {
        atomicAdd(&acc[b * 3 + 0], sA[0] + sA[1] + sA[2] + sA[3]);
        atomicAdd(&acc[b * 3 + 1], sB[0] + sB[1] + sB[2] + sB[3]);
        atomicAdd(&acc[b * 3 + 2], sC[0] + sC[1] + sC[2] + sC[3]);
    }
}

__global__ void k_fin(const float* __restrict__ acc, float* __restrict__ out) {
    float loss = 0.0f;
    for (int b = 0; b < 2; ++b) {
        float inter = acc[b * 3 + 0], spv = acc[b * 3 + 1], stv = acc[b * 3 + 2];
        float dice = (2.0f * inter + SM) / (spv + stv + SM);
        loss += 1.0f - dice;
    }
    out[0] = 0.5f * loss;
}

extern "C" void kernel_launch(void* const* d_in, const int* in_sizes, int n_in,
                              void* d_out, int out_size, void* d_ws, size_t ws_size,
                              hipStream_t stream) {
    (void)in_sizes; (void)n_in; (void)out_size; (void)ws_size;
    const float* pred = (const float*)d_in[0];
    const float* tgt  = (const float*)d_in[1];
    float* out  = (float*)d_out;
    float* meta = (float*)d_ws;
    float* bufA = meta + BUF_OFF;
    float* bufB = bufA + (size_t)4 * NV;

    k_init_meta<<<dim3(1), dim3(256), 0, stream>>>(meta);
    k_flag<<<dim3(1024), dim3(256), 0, stream>>>((const float4*)pred, meta, 2 * NV / 4);
    k_prep<<<dim3(1024), dim3(256), 0, stream>>>((const float4*)pred, (const float4*)tgt,
                                                 meta, (float4*)bufA,
                                                 (float4*)(bufA + (size_t)2 * NV), 2 * NV / 4);

    dim3 sgrid(8 * (DIM / ZC), 4);   // ytiles * zchunks, volumes
    dim3 sblock(16, YT);
    for (int it = 0; it < NITER; ++it) {
        const float* s = (it & 1) ? bufB : bufA;
        float*       d = (it & 1) ? bufA : bufB;
        k_step<<<sgrid, sblock, 0, stream>>>(s, d, meta, it);
    }

    k_dice<<<dim3(512, 2), dim3(256), 0, stream>>>(bufA, meta + ACC_OFF);
    k_fin<<<dim3(1), dim3(1), 0, stream>>>(meta + ACC_OFF, out);
}

// Round 4
// 999.292 us; speedup vs baseline: 2.4077x; 1.2484x over previous
//
#include <hip/hip_runtime.h>
#include <math.h>

#define DIM   128
#define NV    (DIM*DIM*DIM)          // elements per volume; 4 volumes
#define SM    1e-6f
#define NITER 40
#define INV27 (1.0f/27.0f)
#define ACC_OFF  96
#define FLAG_OFF 104
#define BUF_OFF  256                 // floats offset into ws for buffers
#define YT 20                        // thread rows (16 interior + 2 halo each side)
#define ZC 8                         // z outputs per block

typedef _Float16 half8 __attribute__((ext_vector_type(8)));

__device__ __forceinline__ float c01(float v){ return fminf(fmaxf(v, 0.f), 1.f); }

__global__ __launch_bounds__(256)
void k_init_meta(float* meta) { meta[threadIdx.x] = 0.0f; }

__global__ __launch_bounds__(256)
void k_flag(const float4* __restrict__ pred, float* __restrict__ meta, int n4) {
    int stride = gridDim.x * blockDim.x;
    bool hit = false;
    for (int i = blockIdx.x * blockDim.x + threadIdx.x; i < n4; i += stride) {
        float4 p = pred[i];
        hit |= (p.x > 1.f) | (p.y > 1.f) | (p.z > 1.f) | (p.w > 1.f);
    }
    if (hit) meta[FLAG_OFF] = 1.0f;   // same-value racing stores: benign
}

// clip(+optional sigmoid) fp32 inputs -> fp16 buffers. 8 elements/thread.
__global__ __launch_bounds__(256)
void k_prep(const float* __restrict__ pred, const float* __restrict__ tgt,
            const float* __restrict__ meta, _Float16* __restrict__ outP,
            _Float16* __restrict__ outT) {
    const bool sg = (meta[FLAG_OFF] != 0.0f);
    const int idx = blockIdx.x * blockDim.x + threadIdx.x;   // < 2*NV/8
    const int i8 = idx * 8;
    float4 a = *(const float4*)(pred + i8);
    float4 b = *(const float4*)(pred + i8 + 4);
    float pv[8] = {a.x,a.y,a.z,a.w,b.x,b.y,b.z,b.w};
    half8 hp, ht;
    #pragma unroll
    for (int k = 0; k < 8; ++k) {
        float p = pv[k];
        if (sg) p = 1.f / (1.f + __expf(-p));
        hp[k] = (_Float16)c01(p);
    }
    *(half8*)(outP + i8) = hp;
    float4 c = *(const float4*)(tgt + i8);
    float4 d = *(const float4*)(tgt + i8 + 4);
    float tv[8] = {c.x,c.y,c.z,c.w,d.x,d.y,d.z,d.w};
    #pragma unroll
    for (int k = 0; k < 8; ++k) ht[k] = (_Float16)c01(tv[k]);
    *(half8*)(outT + i8) = ht;
}

// Fused skeletonize step, fp16 storage / fp32 math, 1 barrier per plane.
// Block 16x20; thread owns 8 contiguous x (one half8 = 16B load/store per plane).
__global__ __launch_bounds__(320)
void k_step(const _Float16* __restrict__ src, _Float16* __restrict__ dst,
            float* __restrict__ sums, int iter) {
    __shared__ float4 sA4[2][YT][33];   // input row-sums (two float4 halves per thread)
    __shared__ float4 sB4[2][YT][33];   // eroded row-sums
    __shared__ float  sRed[5];
    __shared__ float  sDone;

    const int x    = threadIdx.x;          // 0..15
    const int y    = threadIdx.y;          // 0..19
    const int tid  = y * 16 + x;
    const int lane = tid & 63;
    const int ytile = blockIdx.x & 7;
    const int zch   = blockIdx.x >> 3;     // 0..15
    const int vol   = blockIdx.y;          // 0,1 pred; 2,3 target
    const int g     = vol >> 1;
    const int z0    = zch * ZC;
    const int gy    = ytile * 16 - 2 + y;
    const bool rowIn = (gy >= 0) && (gy < DIM);
    const bool midY  = (y >= 1) && (y <= 18);
    const bool outY  = (y >= 2) && (y <= 17);

    if (tid < 64) {
        bool hit = (tid < iter) && (sums[tid * 2 + g] < SM);
        unsigned long long m = __ballot(hit);
        if (lane == 0) sDone = (m != 0ull) ? 1.0f : 0.0f;
    }
    __syncthreads();
    const bool done = (sDone != 0.0f);

    const _Float16* sp = src + (size_t)vol * NV + (size_t)gy * DIM + x * 8;
    _Float16*       dp = dst + (size_t)vol * NV + (size_t)gy * DIM + x * 8;

    float vm1[8] = {0}, vm2[8] = {0}, vm3[8] = {0};
    float s1[8] = {0}, s2[8] = {0};
    float r2[8] = {0};
    float g1[8] = {0}, g2[8] = {0};
    float localSum = 0.f;

    // prefetch first plane
    half8 hnext = (half8)(_Float16)0.f;
    {
        const int Zf = z0 - 2;
        if (rowIn && Zf >= 0)
            hnext = *(const half8*)(sp + (size_t)Zf * (DIM * DIM));
    }

    for (int Z = z0 - 2; Z <= z0 + ZC + 2; ++Z) {
        const int p = Z & 1;
        float v[8];
        #pragma unroll
        for (int k = 0; k < 8; ++k) v[k] = (float)hnext[k];
        // loaded-plane validity (beyond guards hnext is zero already)
        // issue prefetch of plane Z+1
        hnext = (half8)(_Float16)0.f;
        const int Zn = Z + 1;
        if (rowIn && Zn >= 0 && Zn < DIM && Zn <= z0 + ZC + 1)
            hnext = *(const half8*)(sp + (size_t)Zn * (DIM * DIM));

        // ---- x row-sum via shuffles ----
        float lft = __shfl(v[7], lane - 1); if (x == 0)  lft = 0.f;
        float rgt = __shfl(v[0], lane + 1); if (x == 15) rgt = 0.f;
        float rs[8];
        rs[0] = lft + v[0] + v[1];
        #pragma unroll
        for (int k = 1; k < 7; ++k) rs[k] = v[k-1] + v[k] + v[k+1];
        rs[7] = v[6] + v[7] + rgt;

        sA4[p][y][x]      = make_float4(rs[0], rs[1], rs[2], rs[3]);
        sA4[p][y][16 + x] = make_float4(rs[4], rs[5], rs[6], rs[7]);
        sB4[p][y][x]      = make_float4(r2[0], r2[1], r2[2], r2[3]);
        sB4[p][y][16 + x] = make_float4(r2[4], r2[5], r2[6], r2[7]);
        __syncthreads();

        const int ym = (y > 0) ? y - 1 : 0;
        const int yp = (y < YT - 1) ? y + 1 : YT - 1;
        float4 uA = sA4[p][ym][x], uB = sA4[p][ym][16 + x];
        float4 dA = sA4[p][yp][x], dB = sA4[p][yp][16 + x];
        float u[8] = {uA.x,uA.y,uA.z,uA.w,uB.x,uB.y,uB.z,uB.w};
        float dn[8] = {dA.x,dA.y,dA.z,dA.w,dB.x,dB.y,dB.z,dB.w};
        float sd[8];
        #pragma unroll
        for (int k = 0; k < 8; ++k) sd[k] = u[k] + rs[k] + dn[k];

        const bool erOk = midY && rowIn && (Z - 1 >= 0) && (Z - 1 < DIM);
        float er[8];
        #pragma unroll
        for (int k = 0; k < 8; ++k) {
            float e = (s2[k] + s1[k] + sd[k]) * INV27 - SM;
            er[k] = erOk ? c01(e) : 0.f;
        }
        #pragma unroll
        for (int k = 0; k < 8; ++k) { s2[k] = s1[k]; s1[k] = sd[k]; }

        // ---- x row-sum of eroded -> r2 for next loop's LDS store ----
        float lft2 = __shfl(er[7], lane - 1); if (x == 0)  lft2 = 0.f;
        float rgt2 = __shfl(er[0], lane + 1); if (x == 15) rgt2 = 0.f;
        float r2n[8];
        r2n[0] = lft2 + er[0] + er[1];
        #pragma unroll
        for (int k = 1; k < 7; ++k) r2n[k] = er[k-1] + er[k] + er[k+1];
        r2n[7] = er[6] + er[7] + rgt2;

        // ---- 2D sum of eroded (plane Z-2) from LDS ----
        float4 euA = sB4[p][ym][x], euB = sB4[p][ym][16 + x];
        float4 edA = sB4[p][yp][x], edB = sB4[p][yp][16 + x];
        float eu[8] = {euA.x,euA.y,euA.z,euA.w,euB.x,euB.y,euB.z,euB.w};
        float ed[8] = {edA.x,edA.y,edA.z,edA.w,edB.x,edB.y,edB.z,edB.w};
        float e2[8];
        #pragma unroll
        for (int k = 0; k < 8; ++k) e2[k] = eu[k] + r2[k] + ed[k];

        // ---- opened plane Z-3, emit ----
        const int zo = Z - 3;
        if (zo >= z0 && outY) {
            half8 ho;
            float part = 0.f;
            #pragma unroll
            for (int k = 0; k < 8; ++k) {
                float op = c01((g2[k] + g1[k] + e2[k]) * INV27);
                float nv = vm3[k] * (1.f - op + SM);
                nv = done ? vm3[k] : nv;
                ho[k] = (_Float16)nv;
                part += nv;
            }
            *(half8*)(dp + (size_t)zo * (DIM * DIM)) = ho;
            localSum += part;
        }
        #pragma unroll
        for (int k = 0; k < 8; ++k) {
            g2[k] = g1[k]; g1[k] = e2[k];
            vm3[k] = vm2[k]; vm2[k] = vm1[k]; vm1[k] = v[k];
            r2[k] = r2n[k];
        }
    }

    // ---- block reduce localSum -> sums[iter*2+g] ----
    float s = localSum;
    for (int off = 32; off > 0; off >>= 1) s += __shfl_down(s, off);
    if (lane == 0) sRed[tid >> 6] = s;
    __syncthreads();
    if (tid == 0)
        atomicAdd(&sums[iter * 2 + g], sRed[0] + sRed[1] + sRed[2] + sRed[3] + sRed[4]);
}

// XCD-matched dice reduction: block (bx,by) reads the stripe written by k_step
// blocks with the same (flat % 8) == ytile -> same-XCD L2 dirty hits.
// grid (64, 8): bx = ytile + 8*zc16 ; by = b + 2*zq (zq: quarter of the 16-plane chunk)
__global__ __launch_bounds__(256)
void k_dice(const _Float16* __restrict__ buf, float* __restrict__ acc) {
    __shared__ float sA[4], sB[4], sC[4];
    const int bx = blockIdx.x, by = blockIdx.y;
    const int ytile = bx & 7, zc16 = bx >> 3;
    const int b = by & 1, zq = by >> 1;
    const int y0 = ytile * 16;
    const int z0 = zc16 * 16 + zq * 4;
    const int tid  = threadIdx.x;
    const int lane = tid & 63;
    const int yy = tid >> 4, xg = tid & 15;

    const _Float16* p = buf + (size_t)b * NV;
    const _Float16* t = buf + (size_t)(2 + b) * NV;

    float si = 0.f, spv = 0.f, stv = 0.f;
    #pragma unroll
    for (int zi = 0; zi < 4; ++zi) {
        const size_t off = ((size_t)(z0 + zi) * DIM + (y0 + yy)) * DIM + xg * 8;
        half8 hp = *(const half8*)(p + off);
        half8 ht = *(const half8*)(t + off);
        #pragma unroll
        for (int k = 0; k < 8; ++k) {
            float pv = (float)hp[k], tv = (float)ht[k];
            si += pv * tv; spv += pv; stv += tv;
        }
    }
    for (int off = 32; off > 0; off >>= 1) {
        si  += __shfl_down(si, off);
        spv += __shfl_down(spv, off);
        stv += __shfl_down(stv, off);
    }
    if (lane == 0) { sA[tid >> 6] = si; sB[tid >> 6] = spv; sC[tid >> 6] = stv; }
    __syncthreads();
    if (tid == 0) {
        atomicAdd(&acc[b * 3 + 0], sA[0] + sA[1] + sA[2] + sA[3]);
        atomicAdd(&acc[b * 3 + 1], sB[0] + sB[1] + sB[2] + sB[3]);
        atomicAdd(&acc[b * 3 + 2], sC[0] + sC[1] + sC[2] + sC[3]);
    }
}

__global__ void k_fin(const float* __restrict__ acc, float* __restrict__ out) {
    float loss = 0.0f;
    for (int b = 0; b < 2; ++b) {
        float inter = acc[b * 3 + 0], spv = acc[b * 3 + 1], stv = acc[b * 3 + 2];
        float dice = (2.0f * inter + SM) / (spv + stv + SM);
        loss += 1.0f - dice;
    }
    out[0] = 0.5f * loss;
}

extern "C" void kernel_launch(void* const* d_in, const int* in_sizes, int n_in,
                              void* d_out, int out_size, void* d_ws, size_t ws_size,
                              hipStream_t stream) {
    (void)in_sizes; (void)n_in; (void)out_size; (void)ws_size;
    const float* pred = (const float*)d_in[0];
    const float* tgt  = (const float*)d_in[1];
    float* out  = (float*)d_out;
    float* meta = (float*)d_ws;
    _Float16* bufA = (_Float16*)(meta + BUF_OFF);
    _Float16* bufB = bufA + (size_t)4 * NV;

    k_init_meta<<<dim3(1), dim3(256), 0, stream>>>(meta);
    k_flag<<<dim3(1024), dim3(256), 0, stream>>>((const float4*)pred, meta, 2 * NV / 4);
    k_prep<<<dim3(2 * NV / 8 / 256), dim3(256), 0, stream>>>(
        pred, tgt, meta, bufA, bufA + (size_t)2 * NV);

    dim3 sgrid(8 * (DIM / ZC), 4);   // (ytile + 8*zch, vol) ; XCD = ytile
    dim3 sblock(16, YT);
    for (int it = 0; it < NITER; ++it) {
        const _Float16* s = (it & 1) ? bufB : bufA;
        _Float16*       d = (it & 1) ? bufA : bufB;
        k_step<<<sgrid, sblock, 0, stream>>>(s, d, meta, it);
    }

    k_dice<<<dim3(64, 8), dim3(256), 0, stream>>>(bufA, meta + ACC_OFF);
    k_fin<<<dim3(1), dim3(1), 0, stream>>>(meta + ACC_OFF, out);
}